// Round 1
// baseline (391.699 us; speedup 1.0000x reference)
//
#include <hip/hip_runtime.h>
#include <hip/hip_bf16.h>

// ---------------------------------------------------------------------------
// myGRUCell low-rank fused kernel for MI355X (gfx950).
//
// reference math:
//   xW = x@W  (B,64)      hU = h@U (B,64)
//   r  = sigmoid(xW@W1 + hU@U1 + h*U1d + bias_r)
//   z  = sigmoid(xW@W2 + hU@U2 + h*U2d + bias_gate)
//   rh = r*h;  rhU = rh@U (B,64)
//   c  = tanh(xW@W3 + rhU@U3 + rh*U3d + bias_update)
//   out = z*h + (1-z)*c
//
// Strategy: prep kernel packs weights to bf16, transposed [n][k] so MFMA
// B-fragments are contiguous 16B loads.  Fused kernel: BM=64 rows/block,
// 4 waves, bf16 MFMA 16x16x32 for all GEMMs, fp32 h for elementwise.
// ---------------------------------------------------------------------------

typedef __attribute__((ext_vector_type(8))) short short8;   // 8 x bf16
typedef __attribute__((ext_vector_type(4))) float f32x4;    // MFMA acc
typedef __attribute__((ext_vector_type(4))) float f4;

__device__ __forceinline__ short f2bf(float f) {
  unsigned u = __builtin_bit_cast(unsigned, f);
  u += 0x7FFFu + ((u >> 16) & 1u);          // round-nearest-even
  return (short)(u >> 16);
}

__device__ __forceinline__ f32x4 mfma16(short8 a, short8 b, f32x4 c) {
  return __builtin_amdgcn_mfma_f32_16x16x32_bf16(a, b, c, 0, 0, 0);
}

// LDS tiles are [64 rows][128 k] bf16 (256B row stride).  XOR-swizzle the
// 16B granule with row&7 so a 16-lane column read hits 8 distinct bank slots
// (2-way = free, m136) instead of 16-way conflicting.
__device__ __forceinline__ short8 lds_read_frag(const short* base, int row, int k) {
  return *reinterpret_cast<const short8*>(base + row * 128 + (k ^ ((row & 7) << 3)));
}
__device__ __forceinline__ void lds_write_elem(short* base, int row, int col, short v) {
  base[row * 128 + (col ^ ((row & 7) << 3))] = v;
}

__device__ __forceinline__ float sigm_f(float v) { return 1.f / (1.f + __expf(-v)); }
__device__ __forceinline__ float tanh_f(float v) { return 1.f - 2.f / (__expf(2.f * v) + 1.f); }

// ---------------------------------------------------------------------------
// prep: pack weights to bf16 in d_ws.
//  ws[0      .. 65535 ]  Wt  [64][1024]   Wt[n][k]  = W[k][n]
//  ws[65536  .. 131071]  Ut  [64][1024]   Ut[n][k]  = U[k][n]
//  ws[131072 .. 262143]  P1t [1024][128]  P1t[n][k] = k<64 ? W1[k][n] : U1[k-64][n]
//  ws[262144 .. 393215]  P2t [1024][128]  (W2/U2)
//  ws[393216 .. 524287]  P3t [1024][128]  (W3/U3)
// ---------------------------------------------------------------------------
__global__ void prep_kernel(const float* __restrict__ W,  const float* __restrict__ W1,
                            const float* __restrict__ W2, const float* __restrict__ W3,
                            const float* __restrict__ U,  const float* __restrict__ U1,
                            const float* __restrict__ U2, const float* __restrict__ U3,
                            short* __restrict__ ws) {
  int i = blockIdx.x * blockDim.x + threadIdx.x;  // 0 .. 524287
  float v;
  if (i < 65536) {
    int n = i >> 10, k = i & 1023;
    v = W[k * 64 + n];
  } else if (i < 131072) {
    int j = i - 65536;
    int n = j >> 10, k = j & 1023;
    v = U[k * 64 + n];
  } else {
    int j = i - 131072;
    int sel = j >> 17;          // 0,1,2
    int jj = j & 131071;
    int n = jj >> 7, k = jj & 127;
    const float* Wk = sel == 0 ? W1 : sel == 1 ? W2 : W3;
    const float* Uk = sel == 0 ? U1 : sel == 1 ? U2 : U3;
    v = (k < 64) ? Wk[k * 1024 + n] : Uk[(k - 64) * 1024 + n];
  }
  ws[i] = f2bf(v);
}

// ---------------------------------------------------------------------------
// fused GRU cell kernel. grid = B/64 = 512 blocks, 256 threads (4 waves).
// ---------------------------------------------------------------------------
__global__ __launch_bounds__(256, 2) void gru_fused(
    const float* __restrict__ x, const float* __restrict__ h,
    const float* __restrict__ u1d, const float* __restrict__ u2d,
    const float* __restrict__ u3d,
    const float* __restrict__ biasR, const float* __restrict__ biasZ,
    const float* __restrict__ biasU,
    const short* __restrict__ ws, float* __restrict__ out) {
  const short* Wt  = ws;
  const short* Ut  = ws + 65536;
  const short* P1t = ws + 131072;
  const short* P2t = ws + 262144;
  const short* P3t = ws + 393216;

  __shared__ __align__(16) short sA12[64 * 128];  // [xW | hU]   bf16
  __shared__ __align__(16) short sA3 [64 * 128];  // [xW | rhU]  bf16
  __shared__ __align__(16) short sRH [64 * 128];  // rh col-tile bf16

  const int tid = threadIdx.x;
  const int w   = tid >> 6;      // wave 0..3
  const int l   = tid & 63;
  const int l15 = l & 15;
  const int lg  = l >> 4;        // 0..3
  const int r0  = blockIdx.x * 64;

  // ---- Phase 0: xW (cols 0..63), hU (cols 64..127); wave w owns rows 16w..16w+15
  {
    f32x4 acc[8] = {};
    const int row = r0 + 16 * w + l15;
    const float* xrow = x + (size_t)row * 1024;
    const float* hrow = h + (size_t)row * 1024;
    for (int k0 = 0; k0 < 1024; k0 += 32) {
      const int k = k0 + lg * 8;
      f4 xa = *reinterpret_cast<const f4*>(xrow + k);
      f4 xb = *reinterpret_cast<const f4*>(xrow + k + 4);
      f4 ha = *reinterpret_cast<const f4*>(hrow + k);
      f4 hb = *reinterpret_cast<const f4*>(hrow + k + 4);
      short8 ax, ah;
#pragma unroll
      for (int j = 0; j < 4; ++j) {
        ax[j] = f2bf(xa[j]); ax[4 + j] = f2bf(xb[j]);
        ah[j] = f2bf(ha[j]); ah[4 + j] = f2bf(hb[j]);
      }
#pragma unroll
      for (int cf = 0; cf < 4; ++cf) {
        short8 bw = *reinterpret_cast<const short8*>(Wt + (cf * 16 + l15) * 1024 + k);
        acc[cf] = mfma16(ax, bw, acc[cf]);
      }
#pragma unroll
      for (int cf = 0; cf < 4; ++cf) {
        short8 buf = *reinterpret_cast<const short8*>(Ut + (cf * 16 + l15) * 1024 + k);
        acc[4 + cf] = mfma16(ah, buf, acc[4 + cf]);
      }
    }
    // C layout: row' = lg*4+j, col = cf*16+l15
#pragma unroll
    for (int cf = 0; cf < 8; ++cf) {
#pragma unroll
      for (int j = 0; j < 4; ++j) {
        int rr = 16 * w + lg * 4 + j;
        int cc = cf * 16 + l15;
        short v = f2bf(acc[cf][j]);
        lds_write_elem(sA12, rr, cc, v);
        if (cf < 4) lds_write_elem(sA3, rr, cc, v);   // xW half of A3
      }
    }
  }
  __syncthreads();

  const int wr = w >> 1;          // 0,1 : row half
  const int wc = w & 1;           // 0,1 : col half within tile
  const int m0 = 32 * wr;

  // ---- Phase 1: r -> rh -> accumulate rhU = rh @ U over 8 col-tiles of 128
  f32x4 accU[4] = {};             // rhU rows 16w..16w+15, cols 0..63
  for (int t = 0; t < 8; ++t) {
    const int n0 = t * 128 + wc * 64;
    f32x4 accR[2][4] = {};
#pragma unroll
    for (int k0 = 0; k0 < 128; k0 += 32) {
      short8 a0 = lds_read_frag(sA12, m0 + l15,      k0 + lg * 8);
      short8 a1 = lds_read_frag(sA12, m0 + 16 + l15, k0 + lg * 8);
#pragma unroll
      for (int cf = 0; cf < 4; ++cf) {
        short8 b = *reinterpret_cast<const short8*>(P1t + (n0 + cf * 16 + l15) * 128 + k0 + lg * 8);
        accR[0][cf] = mfma16(a0, b, accR[0][cf]);
        accR[1][cf] = mfma16(a1, b, accR[1][cf]);
      }
    }
#pragma unroll
    for (int rf = 0; rf < 2; ++rf) {
#pragma unroll
      for (int cf = 0; cf < 4; ++cf) {
        int cc = n0 + cf * 16 + l15;
        float d1 = u1d[cc], b_r = biasR[cc];
#pragma unroll
        for (int j = 0; j < 4; ++j) {
          int rr = m0 + rf * 16 + lg * 4 + j;
          float hv = h[(size_t)(r0 + rr) * 1024 + cc];
          float rv = sigm_f(accR[rf][cf][j] + hv * d1 + b_r);
          lds_write_elem(sRH, rr, cc - t * 128, f2bf(rv * hv));
        }
      }
    }
    __syncthreads();
    // rhU += rh_tile @ U[tile,:]; wave w owns rhU rows 16w..16w+15
#pragma unroll
    for (int kk = 0; kk < 128; kk += 32) {
      short8 a = lds_read_frag(sRH, 16 * w + l15, kk + lg * 8);
#pragma unroll
      for (int cf = 0; cf < 4; ++cf) {
        short8 b = *reinterpret_cast<const short8*>(Ut + (cf * 16 + l15) * 1024 + t * 128 + kk + lg * 8);
        accU[cf] = mfma16(a, b, accU[cf]);
      }
    }
    __syncthreads();
  }

  // rhU -> sA3 cols 64..127
#pragma unroll
  for (int cf = 0; cf < 4; ++cf) {
#pragma unroll
    for (int j = 0; j < 4; ++j) {
      int rr = 16 * w + lg * 4 + j;
      lds_write_elem(sA3, rr, 64 + cf * 16 + l15, f2bf(accU[cf][j]));
    }
  }
  __syncthreads();

  // ---- Phase 2: pre_r (recompute), pre_z, c_pre -> out
  for (int t = 0; t < 8; ++t) {
    const int n0 = t * 128 + wc * 64;
    f32x4 aR[2][4] = {}, aZ[2][4] = {}, aC[2][4] = {};
#pragma unroll
    for (int k0 = 0; k0 < 128; k0 += 32) {
      short8 a12_0 = lds_read_frag(sA12, m0 + l15,      k0 + lg * 8);
      short8 a12_1 = lds_read_frag(sA12, m0 + 16 + l15, k0 + lg * 8);
      short8 a3_0  = lds_read_frag(sA3,  m0 + l15,      k0 + lg * 8);
      short8 a3_1  = lds_read_frag(sA3,  m0 + 16 + l15, k0 + lg * 8);
#pragma unroll
      for (int cf = 0; cf < 4; ++cf) {
        int bo = (n0 + cf * 16 + l15) * 128 + k0 + lg * 8;
        short8 b1 = *reinterpret_cast<const short8*>(P1t + bo);
        short8 b2 = *reinterpret_cast<const short8*>(P2t + bo);
        short8 b3 = *reinterpret_cast<const short8*>(P3t + bo);
        aR[0][cf] = mfma16(a12_0, b1, aR[0][cf]);
        aR[1][cf] = mfma16(a12_1, b1, aR[1][cf]);
        aZ[0][cf] = mfma16(a12_0, b2, aZ[0][cf]);
        aZ[1][cf] = mfma16(a12_1, b2, aZ[1][cf]);
        aC[0][cf] = mfma16(a3_0,  b3, aC[0][cf]);
        aC[1][cf] = mfma16(a3_1,  b3, aC[1][cf]);
      }
    }
#pragma unroll
    for (int rf = 0; rf < 2; ++rf) {
#pragma unroll
      for (int cf = 0; cf < 4; ++cf) {
        int cc = n0 + cf * 16 + l15;
        float d1 = u1d[cc], d2 = u2d[cc], d3 = u3d[cc];
        float b_r = biasR[cc], b_z = biasZ[cc], b_u = biasU[cc];
#pragma unroll
        for (int j = 0; j < 4; ++j) {
          int rr = m0 + rf * 16 + lg * 4 + j;
          size_t gi = (size_t)(r0 + rr) * 1024 + cc;
          float hv = h[gi];
          float rv = sigm_f(aR[rf][cf][j] + hv * d1 + b_r);
          float rhv = rv * hv;
          float zv = sigm_f(aZ[rf][cf][j] + hv * d2 + b_z);
          float cv = tanh_f(aC[rf][cf][j] + rhv * d3 + b_u);
          out[gi] = zv * hv + (1.f - zv) * cv;
        }
      }
    }
  }
}

extern "C" void kernel_launch(void* const* d_in, const int* in_sizes, int n_in,
                              void* d_out, int out_size, void* d_ws, size_t ws_size,
                              hipStream_t stream) {
  const float* x   = (const float*)d_in[0];
  const float* h   = (const float*)d_in[1];
  const float* W   = (const float*)d_in[2];
  const float* W1  = (const float*)d_in[3];
  const float* W2  = (const float*)d_in[4];
  const float* W3  = (const float*)d_in[5];
  const float* U   = (const float*)d_in[6];
  const float* U1  = (const float*)d_in[7];
  const float* U2  = (const float*)d_in[8];
  const float* U3  = (const float*)d_in[9];
  const float* u1d = (const float*)d_in[10];
  const float* u2d = (const float*)d_in[11];
  const float* u3d = (const float*)d_in[12];
  const float* bR  = (const float*)d_in[13];
  const float* bZ  = (const float*)d_in[14];
  const float* bU  = (const float*)d_in[15];
  short* ws = (short*)d_ws;

  prep_kernel<<<2048, 256, 0, stream>>>(W, W1, W2, W3, U, U1, U2, U3, ws);
  gru_fused<<<512, 256, 0, stream>>>(x, h, u1d, u2d, u3d, bR, bZ, bU, ws, (float*)d_out);
}